// Round 5
// baseline (397.709 us; speedup 1.0000x reference)
//
#include <hip/hip_runtime.h>
#include <cstdint>
#include <cstddef>

#define G_    4
#define S_    2048
#define D_    2048
#define E_    64
#define NTOK  (G_ * S_)          // 8192
#define CAPM1 63                 // expert_capacity - 1 (c=0 dropped by [..., 1:])
#define COMBINE_SZ ((size_t)NTOK * E_ * CAPM1)   // 33,030,144
#define KSLICES 16
#define KCHUNK  (D_ / KSLICES)   // 128
#define KT      32               // K-depth of one LDS tile
#define NTILES  (KCHUNK / KT)    // 4
#define XPAD    260              // 256 + 4: keeps ds_read_b128 16B-aligned, breaks write conflicts to 4-way

// ---------------------------------------------------------------------------
// Stage 1: partial GEMM. Block: 256 threads -> 256 tokens x 64 experts tile,
// 8x8 per thread (64 acc VGPRs). LDS bytes/MAC = 1 (4x ds_read_b128 per 64
// FMA). Register-prefetch of the next K-tile overlaps global latency with
// compute. Grid: (8192/256, KSLICES) = (32, 16) = 512 blocks -> 2/CU,
// LDS 41.5KB/block -> both blocks resident.
// ---------------------------------------------------------------------------
__global__ __launch_bounds__(256) void gemm_partial_k(
    const float* __restrict__ x, const float* __restrict__ W,
    float* __restrict__ partial)
{
    __shared__ float xs[KT][XPAD];   // [k][token] 33.3 KB
    __shared__ float wls[KT][64];    // [k][expert] 8 KB

    const int tid     = threadIdx.x;
    const int tokBase = blockIdx.x * 256;
    const int kBase   = blockIdx.y * KCHUNK;

    // compute-role indices: thread -> 8 consecutive tokens x 8 consecutive experts
    const int tt = (tid >> 3) * 8;    // token sub-offset 0..248
    const int ee = (tid & 7) * 8;     // expert sub-offset 0..56

    // x-load role: token = (tid>>3) + r*32, k-quad = (tid&7)*4
    const int xrow = tid >> 3;        // 0..31
    const int k4   = (tid & 7) * 4;   // 0..28

    float acc[8][8];
#pragma unroll
    for (int i = 0; i < 8; ++i)
#pragma unroll
        for (int j = 0; j < 8; ++j) acc[i][j] = 0.f;

    float4 xv[8];
    float4 wv[2];

    // prefetch tile 0 into registers
#pragma unroll
    for (int r = 0; r < 8; ++r)
        xv[r] = *reinterpret_cast<const float4*>(
            &x[(size_t)(tokBase + xrow + r * 32) * D_ + (size_t)(kBase + k4)]);
#pragma unroll
    for (int wi = 0; wi < 2; ++wi) {
        const int idx = tid + wi * 256;           // 0..511 float4s of the 32x64 W tile
        wv[wi] = *reinterpret_cast<const float4*>(
            &W[(size_t)(kBase + (idx >> 4)) * E_ + (idx & 15) * 4]);
    }

    for (int t = 0; t < NTILES; ++t) {
        __syncthreads();   // previous tile's readers done
        // registers -> LDS
#pragma unroll
        for (int r = 0; r < 8; ++r) {
            const int ltok = xrow + r * 32;
            xs[k4 + 0][ltok] = xv[r].x;
            xs[k4 + 1][ltok] = xv[r].y;
            xs[k4 + 2][ltok] = xv[r].z;
            xs[k4 + 3][ltok] = xv[r].w;
        }
#pragma unroll
        for (int wi = 0; wi < 2; ++wi) {
            const int idx = tid + wi * 256;
            *reinterpret_cast<float4*>(&wls[idx >> 4][(idx & 15) * 4]) = wv[wi];
        }
        __syncthreads();

        // prefetch tile t+1 while computing tile t
        if (t + 1 < NTILES) {
            const int kt = kBase + (t + 1) * KT;
#pragma unroll
            for (int r = 0; r < 8; ++r)
                xv[r] = *reinterpret_cast<const float4*>(
                    &x[(size_t)(tokBase + xrow + r * 32) * D_ + (size_t)(kt + k4)]);
#pragma unroll
            for (int wi = 0; wi < 2; ++wi) {
                const int idx = tid + wi * 256;
                wv[wi] = *reinterpret_cast<const float4*>(
                    &W[(size_t)(kt + (idx >> 4)) * E_ + (idx & 15) * 4]);
            }
        }

#pragma unroll 8
        for (int k = 0; k < KT; ++k) {
            const float4 a0 = *reinterpret_cast<const float4*>(&xs[k][tt]);
            const float4 a1 = *reinterpret_cast<const float4*>(&xs[k][tt + 4]);
            const float4 b0 = *reinterpret_cast<const float4*>(&wls[k][ee]);
            const float4 b1 = *reinterpret_cast<const float4*>(&wls[k][ee + 4]);
            float A[8], B[8];
            A[0]=a0.x; A[1]=a0.y; A[2]=a0.z; A[3]=a0.w;
            A[4]=a1.x; A[5]=a1.y; A[6]=a1.z; A[7]=a1.w;
            B[0]=b0.x; B[1]=b0.y; B[2]=b0.z; B[3]=b0.w;
            B[4]=b1.x; B[5]=b1.y; B[6]=b1.z; B[7]=b1.w;
#pragma unroll
            for (int i = 0; i < 8; ++i)
#pragma unroll
                for (int j = 0; j < 8; ++j)
                    acc[i][j] += A[i] * B[j];
        }
    }

    float* dst = partial + (size_t)blockIdx.y * ((size_t)NTOK * E_);
#pragma unroll
    for (int i = 0; i < 8; ++i) {
        const size_t row = (size_t)(tokBase + tt + i) * E_;
        *reinterpret_cast<float4*>(&dst[row + ee])     =
            make_float4(acc[i][0], acc[i][1], acc[i][2], acc[i][3]);
        *reinterpret_cast<float4*>(&dst[row + ee + 4]) =
            make_float4(acc[i][4], acc[i][5], acc[i][6], acc[i][7]);
    }
}

// ---------------------------------------------------------------------------
// Stage 2: reduce K-slices, softmax over E=64 (one wave per token, lane=expert),
// top-2 with lowest-index tie-break (matches jax.lax.top_k).
// ---------------------------------------------------------------------------
__global__ __launch_bounds__(256) void softmax_top2_k(
    const float* __restrict__ partial, const float* __restrict__ b,
    int* __restrict__ e1, int* __restrict__ e2,
    float* __restrict__ g1, float* __restrict__ g2)
{
    const int lane = threadIdx.x & 63;
    const int w    = threadIdx.x >> 6;
    const int tok  = blockIdx.x * 4 + w;

    float v = b[lane];
#pragma unroll
    for (int sl = 0; sl < KSLICES; ++sl)
        v += partial[(size_t)sl * NTOK * E_ + (size_t)tok * E_ + lane];

    float m = v;
#pragma unroll
    for (int off = 32; off >= 1; off >>= 1) m = fmaxf(m, __shfl_xor(m, off));
    float p = expf(v - m);
    float s = p;
#pragma unroll
    for (int off = 32; off >= 1; off >>= 1) s += __shfl_xor(s, off);
    p = p / s;

    // top-1
    float bp = p; int bi = lane;
#pragma unroll
    for (int off = 32; off >= 1; off >>= 1) {
        float po = __shfl_xor(bp, off);
        int   io = __shfl_xor(bi, off);
        if (po > bp || (po == bp && io < bi)) { bp = po; bi = io; }
    }
    // top-2 (exclude bi)
    float p2 = (lane == bi) ? -1.0f : p;
    float bp2 = p2; int bi2 = lane;
#pragma unroll
    for (int off = 32; off >= 1; off >>= 1) {
        float po = __shfl_xor(bp2, off);
        int   io = __shfl_xor(bi2, off);
        if (po > bp2 || (po == bp2 && io < bi2)) { bp2 = po; bi2 = io; }
    }

    if (lane == 0) {
        e1[tok] = bi;  e2[tok] = bi2;
        g1[tok] = bp;  g2[tok] = bp2;
    }
}

// ---------------------------------------------------------------------------
// Stage 3: per-group cumulative position (ballot + LDS wave-prefix).
// One block per group g; 1024 threads = 16 waves, each wave owns two 64-token
// stretches. Emits per-token records: recI={e1,e2,p1m1,p2m1}, recF={g1,g2}
// where pXm1 = (pos<=63) ? pos-1 : -1 (column in the 63-wide capacity slice).
// ---------------------------------------------------------------------------
__global__ __launch_bounds__(1024) void route_pos_k(
    const int* __restrict__ e1, const int* __restrict__ e2,
    const float* __restrict__ g1, const float* __restrict__ g2,
    int4* __restrict__ recI, float2* __restrict__ recF,
    float* __restrict__ out)
{
    __shared__ int cnt[2][32][64];   // [k][wave-seg][expert]

    const int g    = blockIdx.x;
    const int lane = threadIdx.x & 63;
    const int wid  = threadIdx.x >> 6;   // 0..15
    const unsigned long long ltmask = ((unsigned long long)1 << lane) - 1;

    int myE[2][2];
    int rank[2][2];

#pragma unroll
    for (int seg = 0; seg < 2; ++seg) {
        const int wseg = seg * 16 + wid;
        const int tok  = g * S_ + wseg * 64 + lane;
        const int ea = e1[tok];
        const int eb = e2[tok];
        myE[seg][0] = ea;
        myE[seg][1] = eb;
#pragma unroll
        for (int k = 0; k < 2; ++k) {
            const int me = k ? eb : ea;
            int r = 0;
            for (int e = 0; e < 64; ++e) {
                unsigned long long mask = __ballot(me == e);
                if (lane == e) cnt[k][wseg][e] = __popcll(mask);
                if (me == e)   r = __popcll(mask & ltmask);
            }
            rank[seg][k] = r;
        }
    }
    __syncthreads();

    // exclusive prefix over the 32 wave-segments, per (k, e)
    if (threadIdx.x < 128) {
        const int k = threadIdx.x >> 6;
        const int e = threadIdx.x & 63;
        int run = 0;
        for (int w = 0; w < 32; ++w) {
            int c = cnt[k][w][e];
            cnt[k][w][e] = run;
            run += c;
        }
    }
    __syncthreads();

#pragma unroll
    for (int seg = 0; seg < 2; ++seg) {
        const int wseg = seg * 16 + wid;
        const int tok  = g * S_ + wseg * 64 + lane;
        int pm1[2];
#pragma unroll
        for (int k = 0; k < 2; ++k) {
            const int e   = myE[seg][k];
            const int pos = cnt[k][wseg][e] + rank[seg][k] + 1;  // 1-based
            pm1[k] = (pos <= CAPM1) ? (pos - 1) : -1;
        }
        recI[tok] = make_int4(myE[seg][0], myE[seg][1], pm1[0], pm1[1]);
        recF[tok] = make_float2(g1[tok], g2[tok]);
    }

    if (g == 0 && threadIdx.x == 0) out[2 * COMBINE_SZ] = 0.0f;  // loss scalar
}

// ---------------------------------------------------------------------------
// Stage 4: materialize the entire output with coalesced float4 stores.
// Decode the combine float4 ONCE; the mask float4 is (v != 0) ? 1 : 0,
// stored at +COMBINE_SZ. Halves the decode work vs decoding both regions.
// ---------------------------------------------------------------------------
__global__ __launch_bounds__(256) void write_all_k(
    const int4* __restrict__ recI, const float2* __restrict__ recF,
    float* __restrict__ out)
{
    const size_t nvec = COMBINE_SZ / 4;   // 8,257,536 float4s (combine region)
    const size_t stride = (size_t)gridDim.x * blockDim.x;

    for (size_t i = (size_t)blockIdx.x * blockDim.x + threadIdx.x;
         i < nvec; i += stride) {
        const size_t f = i * 4;
        const uint32_t fm = (uint32_t)f;

        // row = fm / 63 via magic multiply (valid for fm < 3.6e8)
        uint32_t row = (uint32_t)(((uint64_t)fm * 272696337ULL) >> 34);
        uint32_t c   = fm - row * 63u;

        uint32_t e = row & 63u, tok = row >> 6;
        int4   ri = recI[tok];
        float2 rf = recF[tok];
        int c1 = (e == (uint32_t)ri.x) ? ri.z : -1;
        int c2 = (e == (uint32_t)ri.y) ? ri.w : -1;

        float4 v;
        float* vp = &v.x;
#pragma unroll
        for (int j = 0; j < 4; ++j) {
            if (c == 63u) {   // crossed into next row
                c = 0; ++row;
                e = row & 63u; tok = row >> 6;
                ri = recI[tok]; rf = recF[tok];
                c1 = (e == (uint32_t)ri.x) ? ri.z : -1;
                c2 = (e == (uint32_t)ri.y) ? ri.w : -1;
            }
            vp[j] = ((int)c == c1) ? rf.x : ((int)c == c2) ? rf.y : 0.0f;
            ++c;
        }
        float4 mk;
        mk.x = (v.x != 0.0f) ? 1.0f : 0.0f;
        mk.y = (v.y != 0.0f) ? 1.0f : 0.0f;
        mk.z = (v.z != 0.0f) ? 1.0f : 0.0f;
        mk.w = (v.w != 0.0f) ? 1.0f : 0.0f;
        *reinterpret_cast<float4*>(&out[f]) = v;
        *reinterpret_cast<float4*>(&out[f + COMBINE_SZ]) = mk;
    }
}

// ---------------------------------------------------------------------------
extern "C" void kernel_launch(void* const* d_in, const int* in_sizes, int n_in,
                              void* d_out, int out_size, void* d_ws, size_t ws_size,
                              hipStream_t stream)
{
    const float* x = (const float*)d_in[0];
    const float* W = (const float*)d_in[1];
    const float* b = (const float*)d_in[2];
    float* out = (float*)d_out;

    // Partial logits (KSLICES * 8192 * 64 f32 = 32 MB) live at the head of
    // d_out; consumed by softmax BEFORE write_all_k overwrites the region.
    float* partial = (float*)d_out;

    // Small per-token arrays in d_ws (~320 KB).
    int*    e1   = (int*)d_ws;
    int*    e2   = e1 + NTOK;
    float*  g1   = (float*)(e2 + NTOK);
    float*  g2   = g1 + NTOK;
    int4*   recI = (int4*)(g2 + NTOK);
    float2* recF = (float2*)(recI + NTOK);

    gemm_partial_k<<<dim3(NTOK / 256, KSLICES), 256, 0, stream>>>(x, W, partial);
    softmax_top2_k<<<NTOK / 4, 256, 0, stream>>>(partial, b, e1, e2, g1, g2);
    route_pos_k<<<G_, 1024, 0, stream>>>(e1, e2, g1, g2, recI, recF, out);
    write_all_k<<<2048, 256, 0, stream>>>(recI, recF, out);
}

// Round 7
// 381.369 us; speedup vs baseline: 1.0428x; 1.0428x over previous
//
#include <hip/hip_runtime.h>
#include <cstdint>
#include <cstddef>

#define G_    4
#define S_    2048
#define D_    2048
#define E_    64
#define NTOK  (G_ * S_)          // 8192
#define CAPM1 63                 // expert_capacity - 1 (c=0 dropped by [..., 1:])
#define COMBINE_SZ ((size_t)NTOK * E_ * CAPM1)   // 33,030,144
#define KSLICES 16
#define KCHUNK  (D_ / KSLICES)   // 128
#define KT      32               // K-depth of one LDS tile
#define NTILES  (KCHUNK / KT)    // 4
#define XPAD    260              // 256 + 4: keeps ds_read_b128 16B-aligned, breaks write conflicts to 4-way

typedef float f32x4 __attribute__((ext_vector_type(4)));   // native vector: OK for nontemporal builtins

// ---------------------------------------------------------------------------
// Stage 1: partial GEMM. Block: 256 threads -> 256 tokens x 64 experts tile,
// 8x8 per thread (64 acc VGPRs). LDS bytes/MAC = 1 (4x ds_read_b128 per 64
// FMA). Register-prefetch of the next K-tile overlaps global latency with
// compute. Grid: (8192/256, KSLICES) = (32, 16) = 512 blocks -> 2/CU.
// ---------------------------------------------------------------------------
__global__ __launch_bounds__(256) void gemm_partial_k(
    const float* __restrict__ x, const float* __restrict__ W,
    float* __restrict__ partial)
{
    __shared__ float xs[KT][XPAD];   // [k][token] 33.3 KB
    __shared__ float wls[KT][64];    // [k][expert] 8 KB

    const int tid     = threadIdx.x;
    const int tokBase = blockIdx.x * 256;
    const int kBase   = blockIdx.y * KCHUNK;

    const int tt = (tid >> 3) * 8;    // token sub-offset 0..248
    const int ee = (tid & 7) * 8;     // expert sub-offset 0..56

    const int xrow = tid >> 3;        // 0..31
    const int k4   = (tid & 7) * 4;   // 0..28

    float acc[8][8];
#pragma unroll
    for (int i = 0; i < 8; ++i)
#pragma unroll
        for (int j = 0; j < 8; ++j) acc[i][j] = 0.f;

    float4 xv[8];
    float4 wv[2];

    // prefetch tile 0 into registers
#pragma unroll
    for (int r = 0; r < 8; ++r)
        xv[r] = *reinterpret_cast<const float4*>(
            &x[(size_t)(tokBase + xrow + r * 32) * D_ + (size_t)(kBase + k4)]);
#pragma unroll
    for (int wi = 0; wi < 2; ++wi) {
        const int idx = tid + wi * 256;           // 0..511 float4s of the 32x64 W tile
        wv[wi] = *reinterpret_cast<const float4*>(
            &W[(size_t)(kBase + (idx >> 4)) * E_ + (idx & 15) * 4]);
    }

    for (int t = 0; t < NTILES; ++t) {
        __syncthreads();   // previous tile's readers done
#pragma unroll
        for (int r = 0; r < 8; ++r) {
            const int ltok = xrow + r * 32;
            xs[k4 + 0][ltok] = xv[r].x;
            xs[k4 + 1][ltok] = xv[r].y;
            xs[k4 + 2][ltok] = xv[r].z;
            xs[k4 + 3][ltok] = xv[r].w;
        }
#pragma unroll
        for (int wi = 0; wi < 2; ++wi) {
            const int idx = tid + wi * 256;
            *reinterpret_cast<float4*>(&wls[idx >> 4][(idx & 15) * 4]) = wv[wi];
        }
        __syncthreads();

        if (t + 1 < NTILES) {
            const int kt = kBase + (t + 1) * KT;
#pragma unroll
            for (int r = 0; r < 8; ++r)
                xv[r] = *reinterpret_cast<const float4*>(
                    &x[(size_t)(tokBase + xrow + r * 32) * D_ + (size_t)(kt + k4)]);
#pragma unroll
            for (int wi = 0; wi < 2; ++wi) {
                const int idx = tid + wi * 256;
                wv[wi] = *reinterpret_cast<const float4*>(
                    &W[(size_t)(kt + (idx >> 4)) * E_ + (idx & 15) * 4]);
            }
        }

#pragma unroll 8
        for (int k = 0; k < KT; ++k) {
            const float4 a0 = *reinterpret_cast<const float4*>(&xs[k][tt]);
            const float4 a1 = *reinterpret_cast<const float4*>(&xs[k][tt + 4]);
            const float4 b0 = *reinterpret_cast<const float4*>(&wls[k][ee]);
            const float4 b1 = *reinterpret_cast<const float4*>(&wls[k][ee + 4]);
            float A[8], B[8];
            A[0]=a0.x; A[1]=a0.y; A[2]=a0.z; A[3]=a0.w;
            A[4]=a1.x; A[5]=a1.y; A[6]=a1.z; A[7]=a1.w;
            B[0]=b0.x; B[1]=b0.y; B[2]=b0.z; B[3]=b0.w;
            B[4]=b1.x; B[5]=b1.y; B[6]=b1.z; B[7]=b1.w;
#pragma unroll
            for (int i = 0; i < 8; ++i)
#pragma unroll
                for (int j = 0; j < 8; ++j)
                    acc[i][j] += A[i] * B[j];
        }
    }

    float* dst = partial + (size_t)blockIdx.y * ((size_t)NTOK * E_);
#pragma unroll
    for (int i = 0; i < 8; ++i) {
        const size_t row = (size_t)(tokBase + tt + i) * E_;
        *reinterpret_cast<float4*>(&dst[row + ee])     =
            make_float4(acc[i][0], acc[i][1], acc[i][2], acc[i][3]);
        *reinterpret_cast<float4*>(&dst[row + ee + 4]) =
            make_float4(acc[i][4], acc[i][5], acc[i][6], acc[i][7]);
    }
}

// ---------------------------------------------------------------------------
// Stage 2: reduce K-slices, softmax over E=64 (one wave per token, lane=expert),
// top-2 with lowest-index tie-break (matches jax.lax.top_k).
// ---------------------------------------------------------------------------
__global__ __launch_bounds__(256) void softmax_top2_k(
    const float* __restrict__ partial, const float* __restrict__ b,
    int* __restrict__ e1, int* __restrict__ e2,
    float* __restrict__ g1, float* __restrict__ g2)
{
    const int lane = threadIdx.x & 63;
    const int w    = threadIdx.x >> 6;
    const int tok  = blockIdx.x * 4 + w;

    float v = b[lane];
#pragma unroll
    for (int sl = 0; sl < KSLICES; ++sl)
        v += partial[(size_t)sl * NTOK * E_ + (size_t)tok * E_ + lane];

    float m = v;
#pragma unroll
    for (int off = 32; off >= 1; off >>= 1) m = fmaxf(m, __shfl_xor(m, off));
    float p = expf(v - m);
    float s = p;
#pragma unroll
    for (int off = 32; off >= 1; off >>= 1) s += __shfl_xor(s, off);
    p = p / s;

    // top-1
    float bp = p; int bi = lane;
#pragma unroll
    for (int off = 32; off >= 1; off >>= 1) {
        float po = __shfl_xor(bp, off);
        int   io = __shfl_xor(bi, off);
        if (po > bp || (po == bp && io < bi)) { bp = po; bi = io; }
    }
    // top-2 (exclude bi)
    float p2 = (lane == bi) ? -1.0f : p;
    float bp2 = p2; int bi2 = lane;
#pragma unroll
    for (int off = 32; off >= 1; off >>= 1) {
        float po = __shfl_xor(bp2, off);
        int   io = __shfl_xor(bi2, off);
        if (po > bp2 || (po == bp2 && io < bi2)) { bp2 = po; bi2 = io; }
    }

    if (lane == 0) {
        e1[tok] = bi;  e2[tok] = bi2;
        g1[tok] = bp;  g2[tok] = bp2;
    }
}

// ---------------------------------------------------------------------------
// Stage 3: per-group cumulative position (ballot + LDS wave-prefix).
// Emits per-token records: recI={e1,e2,p1m1,p2m1}, recF={g1,g2}
// where pXm1 = (pos<=63) ? pos-1 : -1 (column in the 63-wide capacity slice).
// ---------------------------------------------------------------------------
__global__ __launch_bounds__(1024) void route_pos_k(
    const int* __restrict__ e1, const int* __restrict__ e2,
    const float* __restrict__ g1, const float* __restrict__ g2,
    int4* __restrict__ recI, float2* __restrict__ recF,
    float* __restrict__ out)
{
    __shared__ int cnt[2][32][64];   // [k][wave-seg][expert]

    const int g    = blockIdx.x;
    const int lane = threadIdx.x & 63;
    const int wid  = threadIdx.x >> 6;   // 0..15
    const unsigned long long ltmask = ((unsigned long long)1 << lane) - 1;

    int myE[2][2];
    int rank[2][2];

#pragma unroll
    for (int seg = 0; seg < 2; ++seg) {
        const int wseg = seg * 16 + wid;
        const int tok  = g * S_ + wseg * 64 + lane;
        const int ea = e1[tok];
        const int eb = e2[tok];
        myE[seg][0] = ea;
        myE[seg][1] = eb;
#pragma unroll
        for (int k = 0; k < 2; ++k) {
            const int me = k ? eb : ea;
            int r = 0;
            for (int e = 0; e < 64; ++e) {
                unsigned long long mask = __ballot(me == e);
                if (lane == e) cnt[k][wseg][e] = __popcll(mask);
                if (me == e)   r = __popcll(mask & ltmask);
            }
            rank[seg][k] = r;
        }
    }
    __syncthreads();

    // exclusive prefix over the 32 wave-segments, per (k, e)
    if (threadIdx.x < 128) {
        const int k = threadIdx.x >> 6;
        const int e = threadIdx.x & 63;
        int run = 0;
        for (int w = 0; w < 32; ++w) {
            int c = cnt[k][w][e];
            cnt[k][w][e] = run;
            run += c;
        }
    }
    __syncthreads();

#pragma unroll
    for (int seg = 0; seg < 2; ++seg) {
        const int wseg = seg * 16 + wid;
        const int tok  = g * S_ + wseg * 64 + lane;
        int pm1[2];
#pragma unroll
        for (int k = 0; k < 2; ++k) {
            const int e   = myE[seg][k];
            const int pos = cnt[k][wseg][e] + rank[seg][k] + 1;  // 1-based
            pm1[k] = (pos <= CAPM1) ? (pos - 1) : -1;
        }
        recI[tok] = make_int4(myE[seg][0], myE[seg][1], pm1[0], pm1[1]);
        recF[tok] = make_float2(g1[tok], g2[tok]);
    }

    if (g == 0 && threadIdx.x == 0) out[2 * COMBINE_SZ] = 0.0f;  // loss scalar
}

// ---------------------------------------------------------------------------
// Stage 4: materialize the entire output with coalesced float4 stores.
// Decode the combine float4 ONCE; mask float4 = (v != 0) at +COMBINE_SZ.
// NONTEMPORAL stores (native ext_vector type): 264 MB written once, never
// re-read by us — skip L2 allocation so streaming writes don't thrash L2.
// ---------------------------------------------------------------------------
__global__ __launch_bounds__(256) void write_all_k(
    const int4* __restrict__ recI, const float2* __restrict__ recF,
    float* __restrict__ out)
{
    const size_t nvec = COMBINE_SZ / 4;   // 8,257,536 float4s (combine region)
    const size_t stride = (size_t)gridDim.x * blockDim.x;

    for (size_t i = (size_t)blockIdx.x * blockDim.x + threadIdx.x;
         i < nvec; i += stride) {
        const size_t f = i * 4;
        const uint32_t fm = (uint32_t)f;

        // row = fm / 63 via magic multiply (valid for fm < 3.6e8)
        uint32_t row = (uint32_t)(((uint64_t)fm * 272696337ULL) >> 34);
        uint32_t c   = fm - row * 63u;

        uint32_t e = row & 63u, tok = row >> 6;
        int4   ri = recI[tok];
        float2 rf = recF[tok];
        int c1 = (e == (uint32_t)ri.x) ? ri.z : -1;
        int c2 = (e == (uint32_t)ri.y) ? ri.w : -1;

        f32x4 v;
#pragma unroll
        for (int j = 0; j < 4; ++j) {
            if (c == 63u) {   // crossed into next row
                c = 0; ++row;
                e = row & 63u; tok = row >> 6;
                ri = recI[tok]; rf = recF[tok];
                c1 = (e == (uint32_t)ri.x) ? ri.z : -1;
                c2 = (e == (uint32_t)ri.y) ? ri.w : -1;
            }
            v[j] = ((int)c == c1) ? rf.x : ((int)c == c2) ? rf.y : 0.0f;
            ++c;
        }
        f32x4 mk;
        mk[0] = (v[0] != 0.0f) ? 1.0f : 0.0f;
        mk[1] = (v[1] != 0.0f) ? 1.0f : 0.0f;
        mk[2] = (v[2] != 0.0f) ? 1.0f : 0.0f;
        mk[3] = (v[3] != 0.0f) ? 1.0f : 0.0f;
        __builtin_nontemporal_store(v,  reinterpret_cast<f32x4*>(&out[f]));
        __builtin_nontemporal_store(mk, reinterpret_cast<f32x4*>(&out[f + COMBINE_SZ]));
    }
}

// ---------------------------------------------------------------------------
extern "C" void kernel_launch(void* const* d_in, const int* in_sizes, int n_in,
                              void* d_out, int out_size, void* d_ws, size_t ws_size,
                              hipStream_t stream)
{
    const float* x = (const float*)d_in[0];
    const float* W = (const float*)d_in[1];
    const float* b = (const float*)d_in[2];
    float* out = (float*)d_out;

    // Partial logits (KSLICES * 8192 * 64 f32 = 32 MB) live at the head of
    // d_out; consumed by softmax BEFORE write_all_k overwrites the region.
    float* partial = (float*)d_out;

    // Small per-token arrays in d_ws (~320 KB).
    int*    e1   = (int*)d_ws;
    int*    e2   = e1 + NTOK;
    float*  g1   = (float*)(e2 + NTOK);
    float*  g2   = g1 + NTOK;
    int4*   recI = (int4*)(g2 + NTOK);
    float2* recF = (float2*)(recI + NTOK);

    gemm_partial_k<<<dim3(NTOK / 256, KSLICES), 256, 0, stream>>>(x, W, partial);
    softmax_top2_k<<<NTOK / 4, 256, 0, stream>>>(partial, b, e1, e2, g1, g2);
    route_pos_k<<<G_, 1024, 0, stream>>>(e1, e2, g1, g2, recI, recF, out);
    write_all_k<<<2048, 256, 0, stream>>>(recI, recF, out);
}